// Round 6
// baseline (478.019 us; speedup 1.0000x reference)
//
#include <hip/hip_runtime.h>

// LSTM: B=8192, T=512, IN=8, H=64, OUT=1
// R6: gate-split 8-wave WGs (512 thr), grid 512 -> 2 WG/CU = 4 waves/SIMD
//     (2x TLP vs R5). Wave w owns units 8w..8w+7, ALL 4 gates, as two
//     gate-interleaved 16-col MFMA tiles: tile0=[i(u0..7)|f(u0..7)],
//     tile1=[g|o]. 6 MFMAs/wave-step, 2 elements/lane. (gate x row) ->
//     (row x gates) fix-up is wave-internal: 4 cndmask + 4 ds_swizzle(xor8)
//     + 8 cndmask, no barrier.
// R5: fused-rcp activation algebra (5 exp2 + 2 rcp per element), bias as
//     persistent MFMA C-operand, pk f32 math.
// R4: x staged via double-buffered LDS chunks (no inner-loop vmem).
// R2: activation scale folded into weights (-log2e i/f/o, +2log2e g).
// MFMA layouts (m89/m91/m120 verified):
//   A[m=lane&15][k=(lane>>4)*8+j], B[k=(lane>>4)*8+j][n=lane&15],
//   C/D: col=lane&15, row=(lane>>4)*4+reg.

typedef _Float16 f16_t;
typedef _Float16 half8 __attribute__((ext_vector_type(8)));
typedef _Float16 half4 __attribute__((ext_vector_type(4)));
typedef __fp16 fp16x2 __attribute__((ext_vector_type(2)));
typedef float floatx2 __attribute__((ext_vector_type(2)));
typedef float floatx4 __attribute__((ext_vector_type(4)));

#define Bn 8192
#define Tn 512
#define INn 8
#define Hn 64
#define BT 16
#define CHUNK 16
#define NCHUNK (Tn / CHUNK)
#define HSTRIDE 72    // f16; 36 words -> b128 h-reads 2-way aliased (free)
#define XTSTRIDE 136  // f16 per tt: 16 rows * 8 + 8 pad; 68 words skew

__device__ __forceinline__ floatx2 act_pair(float zi0, float zi1,
                                            float zf0, float zf1,
                                            float zg0, float zg1,
                                            float zo0, float zo1,
                                            floatx2& chat) {
  const floatx2 one  = {1.f, 1.f};
  const float  K2   = 2.8853900817779268f;  // 2*log2(e)
  const floatx2 K2v  = {K2, K2};
  const floatx2 mK2v = {-K2, -K2};
  const floatx2 clmp = {126.f, 126.f};
  floatx2 A = {__builtin_amdgcn_exp2f(zi0), __builtin_amdgcn_exp2f(zi1)};
  floatx2 G = {__builtin_amdgcn_exp2f(zg0), __builtin_amdgcn_exp2f(zg1)};
  floatx2 F = {__builtin_amdgcn_exp2f(zf0), __builtin_amdgcn_exp2f(zf1)};
  floatx2 O = {__builtin_amdgcn_exp2f(zo0), __builtin_amdgcn_exp2f(zo1)};
  floatx2 PA  = A + one;
  floatx2 PG  = G + one;
  floatx2 PF  = F + one;
  floatx2 PAG = PA * PG;
  floatx2 num = __builtin_elementwise_fma(G, K2v, mK2v) * PF;  // K(G-1)(1+F)
  floatx2 s   = __builtin_elementwise_fma(chat, PAG, num);
  floatx2 P3  = PF * PAG;
  floatx2 R   = {__builtin_amdgcn_rcpf(P3.x), __builtin_amdgcn_rcpf(P3.y)};
  chat = __builtin_elementwise_min(s * R, clmp);
  floatx2 C2 = {__builtin_amdgcn_exp2f(chat.x), __builtin_amdgcn_exp2f(chat.y)};
  floatx2 P4 = (O + one) * (C2 + one);
  floatx2 Rh = {__builtin_amdgcn_rcpf(P4.x), __builtin_amdgcn_rcpf(P4.y)};
  return (C2 - one) * Rh;  // h = o * tanh(c)
}

__global__ __launch_bounds__(512, 4)
void lstm_fused(const float* __restrict__ xg,
                const float* __restrict__ W_ih,
                const float* __restrict__ W_hh,
                const float* __restrict__ b_ih,
                const float* __restrict__ b_hh,
                const float* __restrict__ W_fc,
                const float* __restrict__ b_fc,
                float* __restrict__ out)
{
  __shared__ alignas(16) f16_t hbuf[2][BT][HSTRIDE];
  __shared__ alignas(16) f16_t xlds[2][CHUNK][XTSTRIDE];

  const int tid   = threadIdx.x;
  const int wv    = tid >> 6;     // wave 0..7 -> units 8wv..8wv+7, all gates
  const int lane  = tid & 63;
  const int n     = lane & 15;    // A-row / B-col / D-col index
  const int q     = lane >> 4;    // quad -> rows 4q..4q+3
  const int j     = lane & 7;     // unit index within wave
  const int s     = (lane >> 3) & 1;  // 0: cols i/g side, 1: cols f/o side
  const int bbase = blockIdx.x * BT;

  const float LOG2E = 1.4426950408889634f;

  // ---- B fragments: tile0 cols = [i(u)|f(u)], tile1 = [g(u)|o(u)],
  // u = 8wv + (c&7). K: [0,64)=W_hh, [64,72)=W_ih, [72,96)=0. Pre-scaled.
  const int u = 8 * wv + j;
  const int gate0 = s ? 1 : 0;   // i or f
  const int gate1 = s ? 3 : 2;   // g or o
  half8 bt[2][3];
  #pragma unroll
  for (int tl = 0; tl < 2; ++tl) {
    const int gate = tl ? gate1 : gate0;
    const float sc = (gate == 2) ? (2.f * LOG2E) : (-LOG2E);
    const int Crow = gate * 64 + u;
    #pragma unroll
    for (int kc = 0; kc < 3; ++kc) {
      half8 v;
      #pragma unroll
      for (int e = 0; e < 8; ++e) {
        const int k = kc * 32 + q * 8 + e;
        float w = 0.f;
        if (k < Hn)            w = W_hh[Crow * Hn + k] * sc;
        else if (k < Hn + INn) w = W_ih[Crow * INn + (k - Hn)] * sc;
        v[e] = (f16_t)w;
      }
      bt[tl][kc] = v;
    }
  }

  // ---- scaled biases as persistent MFMA C-operands
  const float sc0 = (gate0 == 2) ? (2.f * LOG2E) : (-LOG2E);
  const float sc1 = (gate1 == 2) ? (2.f * LOG2E) : (-LOG2E);
  const float pb0 = (b_ih[gate0 * 64 + u] + b_hh[gate0 * 64 + u]) * sc0;
  const float pb1 = (b_ih[gate1 * 64 + u] + b_hh[gate1 * 64 + u]) * sc1;
  const floatx4 bias0 = {pb0, pb0, pb0, pb0};
  const floatx4 bias1 = {pb1, pb1, pb1, pb1};

  // ---- LDS init: h0 = 0 in hbuf[0]
  for (int i = tid; i < BT * HSTRIDE; i += 512) ((f16_t*)hbuf[0])[i] = (f16_t)0.f;

  // ---- x staging: one float4 per thread per chunk: (row, tt, half)
  const int row_s = tid >> 5;        // 0..15
  const int tt_s  = (tid >> 1) & 15; // 0..15
  const int hf_s  = tid & 1;         // 0..1
  const float* xps = xg + ((size_t)(bbase + row_s) * Tn + tt_s) * INn + hf_s * 4;

  float4 pa = *(const float4*)(xps);  // chunk 0 preload

  // cell state (scaled domain), rows 4q+2s, 4q+2s+1, unit u
  floatx2 chat = {0.f, 0.f};
  const int ra = 4 * q + 2 * s;   // first row this lane computes

  for (int ch = 0; ch < NCHUNK; ++ch) {
    // ---- write staged chunk to LDS (f16, 8B per thread)
    union { half4 v; fp16x2 h2[2]; } P;
    P.h2[0] = __builtin_amdgcn_cvt_pkrtz(pa.x, pa.y);
    P.h2[1] = __builtin_amdgcn_cvt_pkrtz(pa.z, pa.w);
    *(half4*)&xlds[ch & 1][tt_s][row_s * 8 + hf_s * 4] = P.v;
    __syncthreads();  // xlds chunk + (first iter) hbuf zero visible

    // ---- prefetch next chunk (uniform clamp; hidden over 16 steps)
    const int chn = (ch + 1 < NCHUNK) ? (ch + 1) : 0;
    pa = *(const float4*)(xps + (size_t)chn * CHUNK * INn);

    #pragma unroll
    for (int tt = 0; tt < CHUNK; ++tt) {
      const int p  = tt & 1;
      const int pn = p ^ 1;

      const half8 a0 = *(const half8*)&hbuf[p][n][q * 8];
      const half8 a1 = *(const half8*)&hbuf[p][n][32 + q * 8];
      const half8 a2 = *(const half8*)&xlds[ch & 1][tt][n * 8];

      floatx4 acc0 = __builtin_amdgcn_mfma_f32_16x16x32_f16(a0, bt[0][0], bias0, 0, 0, 0);
      acc0 = __builtin_amdgcn_mfma_f32_16x16x32_f16(a1, bt[0][1], acc0, 0, 0, 0);
      acc0 = __builtin_amdgcn_mfma_f32_16x16x32_f16(a2, bt[0][2], acc0, 0, 0, 0);
      floatx4 acc1 = __builtin_amdgcn_mfma_f32_16x16x32_f16(a0, bt[1][0], bias1, 0, 0, 0);
      acc1 = __builtin_amdgcn_mfma_f32_16x16x32_f16(a1, bt[1][1], acc1, 0, 0, 0);
      acc1 = __builtin_amdgcn_mfma_f32_16x16x32_f16(a2, bt[1][2], acc1, 0, 0, 0);

      // ---- (gate x row) -> (row x gates) wave-internal exchange with lane^8.
      // s=0 lane: acc0=zi rows, acc1=zg rows; needs zf,zo rows {4q,4q+1}.
      // s=1 lane: acc0=zf rows, acc1=zo rows; needs zi,zg rows {4q+2,4q+3}.
      const float sendA = s ? acc0[0] : acc0[2];
      const float sendB = s ? acc0[1] : acc0[3];
      const float sendC = s ? acc1[0] : acc1[2];
      const float sendD = s ? acc1[1] : acc1[3];
      const float rA = __int_as_float(
          __builtin_amdgcn_ds_swizzle(__float_as_int(sendA), 0x201F));
      const float rB = __int_as_float(
          __builtin_amdgcn_ds_swizzle(__float_as_int(sendB), 0x201F));
      const float rC = __int_as_float(
          __builtin_amdgcn_ds_swizzle(__float_as_int(sendC), 0x201F));
      const float rD = __int_as_float(
          __builtin_amdgcn_ds_swizzle(__float_as_int(sendD), 0x201F));
      const float zi0 = s ? rA : acc0[0];
      const float zi1 = s ? rB : acc0[1];
      const float zf0 = s ? acc0[2] : rA;
      const float zf1 = s ? acc0[3] : rB;
      const float zg0 = s ? rC : acc1[0];
      const float zg1 = s ? rD : acc1[1];
      const float zo0 = s ? acc1[2] : rC;
      const float zo1 = s ? acc1[3] : rD;

      const floatx2 h = act_pair(zi0, zi1, zf0, zf1, zg0, zg1, zo0, zo1, chat);

      hbuf[pn][ra + 0][u] = (f16_t)h.x;
      hbuf[pn][ra + 1][u] = (f16_t)h.y;

      __syncthreads();
    }
  }

  // ---- epilogue: out[b] = h_T[b,:] . W_fc + b_fc   (h_T is in hbuf[0])
  if (tid < 64) {
    const int b = lane & 15;
    const int part = lane >> 4;
    float acc = 0.f;
    #pragma unroll
    for (int k = 0; k < 16; ++k) {
      const int uu = part * 16 + k;
      acc = __builtin_fmaf((float)hbuf[0][b][uu], W_fc[uu], acc);
    }
    acc += __shfl_down(acc, 32);
    acc += __shfl_down(acc, 16);
    if (lane < 16) out[bbase + b] = acc + b_fc[0];
  }
}

extern "C" void kernel_launch(void* const* d_in, const int* in_sizes, int n_in,
                              void* d_out, int out_size, void* d_ws, size_t ws_size,
                              hipStream_t stream) {
  const float* x    = (const float*)d_in[0];
  const float* W_ih = (const float*)d_in[1];
  const float* W_hh = (const float*)d_in[2];
  const float* b_ih = (const float*)d_in[3];
  const float* b_hh = (const float*)d_in[4];
  const float* W_fc = (const float*)d_in[5];
  const float* b_fc = (const float*)d_in[6];
  float* out = (float*)d_out;
  dim3 grid(Bn / BT), block(512);
  hipLaunchKernelGGL(lstm_fused, grid, block, 0, stream,
                     x, W_ih, W_hh, b_ih, b_hh, W_fc, b_fc, out);
}

// Round 7
// 468.162 us; speedup vs baseline: 1.0211x; 1.0211x over previous
//
#include <hip/hip_runtime.h>

// LSTM: B=8192, T=512, IN=8, H=64, OUT=1
// R7: shrink the phase-aligned per-step floor (LDS pipe + barrier):
//     (a) x removed from LDS: per-lane global prefetch (CHUNK=4) into f16
//         registers; kills the a2 ds_read_b128, xlds writes, staging
//         conflicts and chunk barriers. Loads issue ~1 step before the
//         barrier that drains them -> latency hidden.
//     (b) anti-phase stagger: odd WGs s_sleep ~900cyc at start so the two
//         co-resident WGs per CU hit barriers out of phase.
// R5: fused-rcp activation algebra (5 exp2 + 2 rcp per element), bias as
//     persistent MFMA C-operand, pk f32 math. (4-wave WG, 16 units/wave.)
// R2: activation scale folded into weights (-log2e i/f/o, +2log2e g).
// MFMA layouts (m89/m91/m120 verified):
//   A[m=lane&15][k=(lane>>4)*8+j], B[k=(lane>>4)*8+j][n=lane&15],
//   C/D: col=lane&15, row=(lane>>4)*4+reg.

typedef _Float16 f16_t;
typedef _Float16 half8 __attribute__((ext_vector_type(8)));
typedef __fp16 fp16x2 __attribute__((ext_vector_type(2)));
typedef float floatx2 __attribute__((ext_vector_type(2)));
typedef float floatx4 __attribute__((ext_vector_type(4)));

#define Bn 8192
#define Tn 512
#define INn 8
#define Hn 64
#define BT 16
#define CHUNK 4
#define NCHUNK (Tn / CHUNK)
#define HSTRIDE 72    // f16; 36 words -> b128 h-reads 2-way aliased (free)

__device__ __forceinline__ floatx2 act_pair(float zi0, float zi1,
                                            float zf0, float zf1,
                                            float zg0, float zg1,
                                            float zo0, float zo1,
                                            floatx2& chat) {
  const floatx2 one  = {1.f, 1.f};
  const float  K2   = 2.8853900817779268f;  // 2*log2(e)
  const floatx2 K2v  = {K2, K2};
  const floatx2 mK2v = {-K2, -K2};
  const floatx2 clmp = {126.f, 126.f};
  floatx2 A = {__builtin_amdgcn_exp2f(zi0), __builtin_amdgcn_exp2f(zi1)};
  floatx2 G = {__builtin_amdgcn_exp2f(zg0), __builtin_amdgcn_exp2f(zg1)};
  floatx2 F = {__builtin_amdgcn_exp2f(zf0), __builtin_amdgcn_exp2f(zf1)};
  floatx2 O = {__builtin_amdgcn_exp2f(zo0), __builtin_amdgcn_exp2f(zo1)};
  floatx2 PA  = A + one;
  floatx2 PG  = G + one;
  floatx2 PF  = F + one;
  floatx2 PAG = PA * PG;
  floatx2 num = __builtin_elementwise_fma(G, K2v, mK2v) * PF;  // K(G-1)(1+F)
  floatx2 s   = __builtin_elementwise_fma(chat, PAG, num);
  floatx2 P3  = PF * PAG;
  floatx2 R   = {__builtin_amdgcn_rcpf(P3.x), __builtin_amdgcn_rcpf(P3.y)};
  chat = __builtin_elementwise_min(s * R, clmp);
  floatx2 C2 = {__builtin_amdgcn_exp2f(chat.x), __builtin_amdgcn_exp2f(chat.y)};
  floatx2 P4 = (O + one) * (C2 + one);
  floatx2 Rh = {__builtin_amdgcn_rcpf(P4.x), __builtin_amdgcn_rcpf(P4.y)};
  return (C2 - one) * Rh;  // h = o * tanh(c)
}

__global__ __launch_bounds__(256, 2)
void lstm_fused(const float* __restrict__ xg,
                const float* __restrict__ W_ih,
                const float* __restrict__ W_hh,
                const float* __restrict__ b_ih,
                const float* __restrict__ b_hh,
                const float* __restrict__ W_fc,
                const float* __restrict__ b_fc,
                float* __restrict__ out)
{
  __shared__ alignas(16) f16_t hbuf[2][BT][HSTRIDE];

  // anti-phase stagger: odd WGs start ~900 cyc late so the two co-resident
  // WGs per CU hit their per-step barriers out of phase.
  if (blockIdx.x & 1) {
    __builtin_amdgcn_s_sleep(7);
    __builtin_amdgcn_s_sleep(7);
  }

  const int tid   = threadIdx.x;
  const int wv    = tid >> 6;     // wave 0..3 -> hidden units 16wv..16wv+15
  const int lane  = tid & 63;
  const int n     = lane & 15;    // A-row (batch) / B-col / D-col index
  const int q     = lane >> 4;    // quad
  const int bbase = blockIdx.x * BT;

  const float LOG2E = 1.4426950408889634f;

  // ---- B fragments (weights), pre-scaled, resident in VGPRs/AGPRs.
  // Gate g in {i,f,g,o}: column C = 64*g + 16*wv + n.
  // K layout: k in [0,64) = W_hh cols, [64,72) = W_ih cols, [72,96) = 0.
  half8 bf[4][3];
  #pragma unroll
  for (int g = 0; g < 4; ++g) {
    const float sc = (g == 2) ? (2.f * LOG2E) : (-LOG2E);
    const int C = g * 64 + wv * 16 + n;
    #pragma unroll
    for (int c = 0; c < 3; ++c) {
      half8 v;
      #pragma unroll
      for (int e = 0; e < 8; ++e) {
        const int k = c * 32 + q * 8 + e;
        float w = 0.f;
        if (k < Hn)            w = W_hh[C * Hn + k] * sc;
        else if (k < Hn + INn) w = W_ih[C * INn + (k - Hn)] * sc;
        v[e] = (f16_t)w;
      }
      bf[g][c] = v;
    }
  }

  // ---- scaled biases -> persistent MFMA C-operand registers
  const int u = wv * 16 + n;  // this lane's hidden unit (acc column)
  const float pb_i = -(b_ih[u]       + b_hh[u])       * LOG2E;
  const float pb_f = -(b_ih[64 + u]  + b_hh[64 + u])  * LOG2E;
  const float pb_g =  (b_ih[128 + u] + b_hh[128 + u]) * (2.f * LOG2E);
  const float pb_o = -(b_ih[192 + u] + b_hh[192 + u]) * LOG2E;
  const floatx4 bi  = {pb_i, pb_i, pb_i, pb_i};
  const floatx4 bfv = {pb_f, pb_f, pb_f, pb_f};
  const floatx4 bg  = {pb_g, pb_g, pb_g, pb_g};
  const floatx4 bo  = {pb_o, pb_o, pb_o, pb_o};

  // ---- LDS init: h0 = 0 in hbuf[0]
  for (int i = tid; i < BT * HSTRIDE; i += 256) ((f16_t*)hbuf[0])[i] = (f16_t)0.f;

  // ---- x: per-lane global prefetch, one chunk (4 steps) ahead.
  // Each lane loads its batch row n's 8 inputs for 4 steps (8 float4 loads);
  // quads duplicate addresses -> merged in-wave / L1-served.
  const float* xrow = xg + (size_t)(bbase + n) * Tn * INn;
  float4 pf[8];
  #pragma unroll
  for (int i = 0; i < 8; ++i)
    pf[i] = *(const float4*)(xrow + (i >> 1) * INn + (i & 1) * 4);

  floatx2 chat01 = {0.f, 0.f};  // scaled cell state, rows q*4+{0,1}
  floatx2 chat23 = {0.f, 0.f};  // rows q*4+{2,3}

  __syncthreads();  // hbuf zero visible

  for (int ch = 0; ch < NCHUNK; ++ch) {
    // ---- convert this chunk's x to f16 fragments
    half8 xf[CHUNK];
    #pragma unroll
    for (int s = 0; s < CHUNK; ++s) {
      union { half8 v; fp16x2 h2[4]; } P;
      P.h2[0] = __builtin_amdgcn_cvt_pkrtz(pf[2 * s].x,     pf[2 * s].y);
      P.h2[1] = __builtin_amdgcn_cvt_pkrtz(pf[2 * s].z,     pf[2 * s].w);
      P.h2[2] = __builtin_amdgcn_cvt_pkrtz(pf[2 * s + 1].x, pf[2 * s + 1].y);
      P.h2[3] = __builtin_amdgcn_cvt_pkrtz(pf[2 * s + 1].z, pf[2 * s + 1].w);
      xf[s] = P.v;
    }

    // ---- prefetch next chunk (uniform wrap; drained at most once/chunk)
    const int chn = (ch + 1 < NCHUNK) ? (ch + 1) : 0;
    #pragma unroll
    for (int i = 0; i < 8; ++i)
      pf[i] = *(const float4*)(xrow + ((size_t)chn * CHUNK + (i >> 1)) * INn
                               + (i & 1) * 4);

    #pragma unroll
    for (int tt = 0; tt < CHUNK; ++tt) {
      const int p  = tt & 1;   // CHUNK even -> global parity == tt&1
      const int pn = p ^ 1;

      const half8 a0 = *(const half8*)&hbuf[p][n][q * 8];
      const half8 a1 = *(const half8*)&hbuf[p][n][32 + q * 8];
      const half8 a2 = xf[tt];

      // bias regs as first-MFMA C operand (D != C): no per-step acc init
      floatx4 ai = __builtin_amdgcn_mfma_f32_16x16x32_f16(a0, bf[0][0], bi, 0, 0, 0);
      ai = __builtin_amdgcn_mfma_f32_16x16x32_f16(a1, bf[0][1], ai, 0, 0, 0);
      ai = __builtin_amdgcn_mfma_f32_16x16x32_f16(a2, bf[0][2], ai, 0, 0, 0);
      floatx4 af = __builtin_amdgcn_mfma_f32_16x16x32_f16(a0, bf[1][0], bfv, 0, 0, 0);
      af = __builtin_amdgcn_mfma_f32_16x16x32_f16(a1, bf[1][1], af, 0, 0, 0);
      af = __builtin_amdgcn_mfma_f32_16x16x32_f16(a2, bf[1][2], af, 0, 0, 0);
      floatx4 ag = __builtin_amdgcn_mfma_f32_16x16x32_f16(a0, bf[2][0], bg, 0, 0, 0);
      ag = __builtin_amdgcn_mfma_f32_16x16x32_f16(a1, bf[2][1], ag, 0, 0, 0);
      ag = __builtin_amdgcn_mfma_f32_16x16x32_f16(a2, bf[2][2], ag, 0, 0, 0);
      floatx4 ao = __builtin_amdgcn_mfma_f32_16x16x32_f16(a0, bf[3][0], bo, 0, 0, 0);
      ao = __builtin_amdgcn_mfma_f32_16x16x32_f16(a1, bf[3][1], ao, 0, 0, 0);
      ao = __builtin_amdgcn_mfma_f32_16x16x32_f16(a2, bf[3][2], ao, 0, 0, 0);

      const floatx2 h01 = act_pair(ai[0], ai[1], af[0], af[1],
                                   ag[0], ag[1], ao[0], ao[1], chat01);
      const floatx2 h23 = act_pair(ai[2], ai[3], af[2], af[3],
                                   ag[2], ag[3], ao[2], ao[3], chat23);

      hbuf[pn][q * 4 + 0][u] = (f16_t)h01.x;
      hbuf[pn][q * 4 + 1][u] = (f16_t)h01.y;
      hbuf[pn][q * 4 + 2][u] = (f16_t)h23.x;
      hbuf[pn][q * 4 + 3][u] = (f16_t)h23.y;

      __syncthreads();
    }
  }

  // ---- epilogue: out[b] = h_T[b,:] . W_fc + b_fc   (h_T is in hbuf[0])
  if (tid < 64) {
    const int b = lane & 15;
    const int part = lane >> 4;
    float acc = 0.f;
    #pragma unroll
    for (int k = 0; k < 16; ++k) {
      const int uu = part * 16 + k;
      acc = __builtin_fmaf((float)hbuf[0][b][uu], W_fc[uu], acc);
    }
    acc += __shfl_down(acc, 32);
    acc += __shfl_down(acc, 16);
    if (lane < 16) out[bbase + b] = acc + b_fc[0];
  }
}

extern "C" void kernel_launch(void* const* d_in, const int* in_sizes, int n_in,
                              void* d_out, int out_size, void* d_ws, size_t ws_size,
                              hipStream_t stream) {
  const float* x    = (const float*)d_in[0];
  const float* W_ih = (const float*)d_in[1];
  const float* W_hh = (const float*)d_in[2];
  const float* b_ih = (const float*)d_in[3];
  const float* b_hh = (const float*)d_in[4];
  const float* W_fc = (const float*)d_in[5];
  const float* b_fc = (const float*)d_in[6];
  float* out = (float*)d_out;
  dim3 grid(Bn / BT), block(256);
  hipLaunchKernelGGL(lstm_fused, grid, block, 0, stream,
                     x, W_ih, W_hh, b_ih, b_hh, W_fc, b_fc, out);
}